// Round 8
// baseline (209.077 us; speedup 1.0000x reference)
//
#include <hip/hip_runtime.h>

typedef __bf16 bf16;
typedef __attribute__((ext_vector_type(4))) __bf16 bf16x4;
typedef __attribute__((ext_vector_type(8))) __bf16 bf16x8;
typedef __attribute__((ext_vector_type(4))) float f32x4;

#define MFMA(A,B,C) __builtin_amdgcn_mfma_f32_16x16x32_bf16(A,B,C,0,0,0)

#define SEQ 2048
#define EMB 512
#define HD  64
#define SCALE 22.627416997969522f  // sqrt(512): scores are divided by E^-0.5
// Online-softmax seed: not -inf (fast-math folds inf constants to poison).
#define NEG_SEED -3.0e4f
#define LCAP 16                    // per-query candidate ring (power of 2)

// ---------------------------------------------------------------------------
// One-shot fp32 -> bf16 hi/lo conversion (x, W_qkv) and bf16 (W_out).
// Also zeroes the Vs accumulator (gemm_qkv atomicAdds into it).
// ---------------------------------------------------------------------------
__global__ __launch_bounds__(256)
void convert_kernel(const float* __restrict__ x, const float* __restrict__ Wqkv,
                    const float* __restrict__ Wout,
                    bf16* __restrict__ Xh, bf16* __restrict__ Xl,
                    bf16* __restrict__ Wqh, bf16* __restrict__ Wql,
                    bf16* __restrict__ Wo, float* __restrict__ Vs) {
  if (blockIdx.x < 8) Vs[blockIdx.x * 256 + threadIdx.x] = 0.f;  // 32*64 floats
  const int NX = 8192 * 512 / 4;   // f32x4 chunks
  const int NW = 1536 * 512 / 4;
  const int NO = 512 * 512 / 4;
  const int stride = gridDim.x * 256;
  for (int i = blockIdx.x * 256 + threadIdx.x; i < NX + NW + NO; i += stride) {
    const float* src; bf16 *dh, *dl; int j; bool haslo;
    if (i < NX)           { src = x;    dh = Xh;  dl = Xl;  j = i;           haslo = true; }
    else if (i < NX + NW) { src = Wqkv; dh = Wqh; dl = Wql; j = i - NX;      haslo = true; }
    else                  { src = Wout; dh = Wo;  dl = Wo;  j = i - NX - NW; haslo = false; }
    f32x4 v = *(const f32x4*)&src[(size_t)j * 4];
    bf16x4 h4, l4;
#pragma unroll
    for (int r = 0; r < 4; ++r) {
      bf16 h = (bf16)v[r]; h4[r] = h; l4[r] = (bf16)(v[r] - (float)h);
    }
    *(bf16x4*)&dh[(size_t)j * 4] = h4;
    if (haslo) *(bf16x4*)&dl[(size_t)j * 4] = l4;
  }
}

// ---------------------------------------------------------------------------
// QKV projection: bf16 hi/lo GEMM, 128x64 blocks (B-staging amortized 2x,
// MFMA:ds_read 2:1). Same 64-wide n => epilogue routing unchanged; per-element
// MFMA K-order unchanged => bit-identical to the 64x64 version.
// ---------------------------------------------------------------------------
__global__ __launch_bounds__(256, 3)
void gemm_qkv(const bf16* __restrict__ Xh, const bf16* __restrict__ Xl,
              const bf16* __restrict__ Wh, const bf16* __restrict__ Wl,
              const float* __restrict__ bias,
              bf16* __restrict__ Qh, bf16* __restrict__ Ql,
              bf16* __restrict__ Kh, bf16* __restrict__ Kl,
              bf16* __restrict__ Vrm, float* __restrict__ Vs) {
  __shared__ __align__(16) bf16 Ah[128][64], Al[128][64];
  __shared__ __align__(16) bf16 Bh[64][64],  Bl[64][64];
  const int tid  = threadIdx.x;
  const int lane = tid & 63, wave = tid >> 6;
  const int lin = blockIdx.x;                // 1536 blocks
  const int xcd = lin & 7;
  const int w_  = lin >> 3;                  // 0..191
  const int m0 = ((w_ & 7) + xcd * 8) * 128; // 64 m-blocks, 8 per XCD stripe
  const int n0 = (w_ >> 3) * 64;             // 0..23
  const bool isV = ((n0 % 192) == 128);      // V third: hi-only suffices
  const int wm = wave * 32;                  // wave owns 32 m-rows x 64 n
  const int c = lane & 15, quad = lane >> 4;
  const int sr   = tid >> 3;                 // 0..31 staging row
  const int scol = (tid & 7) * 8;
  const int sphy = ((tid & 7) ^ (sr & 7)) * 8;   // (sr+32k)&7 == sr&7

  const f32x4 zero = {0.f, 0.f, 0.f, 0.f};
  f32x4 acc[2][4];
#pragma unroll
  for (int mt = 0; mt < 2; ++mt)
#pragma unroll
    for (int nt = 0; nt < 4; ++nt) acc[mt][nt] = zero;

  for (int k0 = 0; k0 < 512; k0 += 64) {
    *(bf16x8*)&Ah[sr      ][sphy] = *(const bf16x8*)&Xh[(size_t)(m0 + sr      ) * 512 + k0 + scol];
    *(bf16x8*)&Ah[sr + 32 ][sphy] = *(const bf16x8*)&Xh[(size_t)(m0 + sr + 32 ) * 512 + k0 + scol];
    *(bf16x8*)&Ah[sr + 64 ][sphy] = *(const bf16x8*)&Xh[(size_t)(m0 + sr + 64 ) * 512 + k0 + scol];
    *(bf16x8*)&Ah[sr + 96 ][sphy] = *(const bf16x8*)&Xh[(size_t)(m0 + sr + 96 ) * 512 + k0 + scol];
    *(bf16x8*)&Bh[sr      ][sphy] = *(const bf16x8*)&Wh[(size_t)(n0 + sr      ) * 512 + k0 + scol];
    *(bf16x8*)&Bh[sr + 32 ][sphy] = *(const bf16x8*)&Wh[(size_t)(n0 + sr + 32 ) * 512 + k0 + scol];
    if (!isV) {
      *(bf16x8*)&Al[sr      ][sphy] = *(const bf16x8*)&Xl[(size_t)(m0 + sr      ) * 512 + k0 + scol];
      *(bf16x8*)&Al[sr + 32 ][sphy] = *(const bf16x8*)&Xl[(size_t)(m0 + sr + 32 ) * 512 + k0 + scol];
      *(bf16x8*)&Al[sr + 64 ][sphy] = *(const bf16x8*)&Xl[(size_t)(m0 + sr + 64 ) * 512 + k0 + scol];
      *(bf16x8*)&Al[sr + 96 ][sphy] = *(const bf16x8*)&Xl[(size_t)(m0 + sr + 96 ) * 512 + k0 + scol];
      *(bf16x8*)&Bl[sr      ][sphy] = *(const bf16x8*)&Wl[(size_t)(n0 + sr      ) * 512 + k0 + scol];
      *(bf16x8*)&Bl[sr + 32 ][sphy] = *(const bf16x8*)&Wl[(size_t)(n0 + sr + 32 ) * 512 + k0 + scol];
    }
    __syncthreads();
#pragma unroll
    for (int ks = 0; ks < 64; ks += 32) {
      const int px = (((ks >> 3) + quad) ^ (c & 7)) * 8;
      bf16x8 ah0 = *(bf16x8*)&Ah[wm + c     ][px];
      bf16x8 ah1 = *(bf16x8*)&Ah[wm + 16 + c][px];
      bf16x8 bh[4];
#pragma unroll
      for (int nt = 0; nt < 4; ++nt) bh[nt] = *(bf16x8*)&Bh[nt * 16 + c][px];
      if (isV) {
#pragma unroll
        for (int nt = 0; nt < 4; ++nt) {
          acc[0][nt] = MFMA(ah0, bh[nt], acc[0][nt]);
          acc[1][nt] = MFMA(ah1, bh[nt], acc[1][nt]);
        }
      } else {
        bf16x8 al0 = *(bf16x8*)&Al[wm + c     ][px];
        bf16x8 al1 = *(bf16x8*)&Al[wm + 16 + c][px];
        bf16x8 bl[4];
#pragma unroll
        for (int nt = 0; nt < 4; ++nt) bl[nt] = *(bf16x8*)&Bl[nt * 16 + c][px];
#pragma unroll
        for (int nt = 0; nt < 4; ++nt) {
          acc[0][nt] = MFMA(ah0, bh[nt], acc[0][nt]);
          acc[0][nt] = MFMA(al0, bh[nt], acc[0][nt]);
          acc[0][nt] = MFMA(ah0, bl[nt], acc[0][nt]);
          acc[1][nt] = MFMA(ah1, bh[nt], acc[1][nt]);
          acc[1][nt] = MFMA(al1, bh[nt], acc[1][nt]);
          acc[1][nt] = MFMA(ah1, bl[nt], acc[1][nt]);
        }
      }
    }
    __syncthreads();
  }

  if (isV) {
#pragma unroll
    for (int nt = 0; nt < 4; ++nt) {
      const int n = n0 + nt * 16 + c;
      const float bv = bias[n];
      const int h = n / 192, d = n % 192 - 128;
      const size_t bh_ = (size_t)((m0 >> 11) * 8 + h);   // 128-row block never crosses batch
      float csum = 0.f;
#pragma unroll
      for (int mt = 0; mt < 2; ++mt)
#pragma unroll
        for (int r = 0; r < 4; ++r) {
          const int m = m0 + wm + mt * 16 + quad * 4 + r;
          const int s = m & 2047;
          float v = acc[mt][nt][r] + bv;
          Vrm[(bh_ * SEQ + s) * HD + d] = (bf16)v;
          csum += v;
        }
      csum += __shfl_xor(csum, 16, 64);
      csum += __shfl_xor(csum, 32, 64);
      if (quad == 0) atomicAdd(&Vs[bh_ * HD + d], csum);
    }
  } else {
#pragma unroll
    for (int mt = 0; mt < 2; ++mt) {
#pragma unroll
      for (int nt = 0; nt < 4; ++nt) {
        const int n = n0 + nt * 16 + c;
        const float bv = bias[n];
#pragma unroll
        for (int r = 0; r < 4; ++r) {
          const int m = m0 + wm + mt * 16 + quad * 4 + r;
          float v = acc[mt][nt][r] + bv;
          const int h = n / 192, t = n % 192;
          const size_t bh_ = (size_t)((m >> 11) * 8 + h);
          const int s = m & 2047;
          if (t < 64) {
            float q = v * SCALE;
            bf16 hi = (bf16)q;
            float lo = q - (float)hi;
            size_t idx = (bh_ * SEQ + s) * HD + t;
            Qh[idx] = hi; Ql[idx] = (bf16)lo;
          } else {
            bf16 hi = (bf16)v;
            float lo = v - (float)hi;
            size_t idx = (bh_ * SEQ + s) * HD + (t - 64);
            Kh[idx] = hi; Kl[idx] = (bf16)lo;
          }
        }
      }
    }
  }
}

// ---------------------------------------------------------------------------
// Output projection: bf16 x bf16 (pre-converted Wo), fp32 out. Same XOR-swz.
// ---------------------------------------------------------------------------
__global__ __launch_bounds__(256)
void gemm_out(const bf16* __restrict__ A, const bf16* __restrict__ Wo,
              const float* __restrict__ bias, float* __restrict__ C) {
  __shared__ __align__(16) bf16 As[64][64];
  __shared__ __align__(16) bf16 Bs[64][64];
  const int tid  = threadIdx.x;
  const int lane = tid & 63, wave = tid >> 6;
  const int lin = blockIdx.x + gridDim.x * blockIdx.y;
  const int xcd = lin & 7;
  const int w_  = lin >> 3;                  // 0..127
  const int m0 = ((w_ & 15) + xcd * 16) * 64;
  const int n0 = (w_ >> 4) * 64;
  const int wm = (wave >> 1) * 32, wn = (wave & 1) * 32;
  const int c = lane & 15, quad = lane >> 4;
  const int sr   = tid >> 3;
  const int scol = (tid & 7) * 8;
  const int sphy = ((tid & 7) ^ (sr & 7)) * 8;

  const f32x4 zero = {0.f, 0.f, 0.f, 0.f};
  f32x4 acc[2][2];
  acc[0][0] = zero; acc[0][1] = zero; acc[1][0] = zero; acc[1][1] = zero;

  for (int k0 = 0; k0 < 512; k0 += 64) {
    *(bf16x8*)&As[sr][sphy]      = *(const bf16x8*)&A [(size_t)(m0 + sr     ) * 512 + k0 + scol];
    *(bf16x8*)&As[sr + 32][sphy] = *(const bf16x8*)&A [(size_t)(m0 + sr + 32) * 512 + k0 + scol];
    *(bf16x8*)&Bs[sr][sphy]      = *(const bf16x8*)&Wo[(size_t)(n0 + sr     ) * 512 + k0 + scol];
    *(bf16x8*)&Bs[sr + 32][sphy] = *(const bf16x8*)&Wo[(size_t)(n0 + sr + 32) * 512 + k0 + scol];
    __syncthreads();
#pragma unroll
    for (int ks = 0; ks < 64; ks += 32) {
      const int px = (((ks >> 3) + quad) ^ (c & 7)) * 8;
      bf16x8 a0 = *(bf16x8*)&As[wm + c     ][px];
      bf16x8 a1 = *(bf16x8*)&As[wm + 16 + c][px];
      bf16x8 b0 = *(bf16x8*)&Bs[wn + c     ][px];
      bf16x8 b1 = *(bf16x8*)&Bs[wn + 16 + c][px];
      acc[0][0] = MFMA(a0, b0, acc[0][0]);
      acc[0][1] = MFMA(a0, b1, acc[0][1]);
      acc[1][0] = MFMA(a1, b0, acc[1][0]);
      acc[1][1] = MFMA(a1, b1, acc[1][1]);
    }
    __syncthreads();
  }

#pragma unroll
  for (int mt = 0; mt < 2; ++mt) {
#pragma unroll
    for (int nt = 0; nt < 2; ++nt) {
      const int n = n0 + wn + nt * 16 + c;
      const float bv = bias[n];
#pragma unroll
      for (int r = 0; r < 4; ++r) {
        const int m = m0 + wm + mt * 16 + quad * 4 + r;
        C[(size_t)m * 512 + n] = acc[mt][nt][r] + bv;
      }
    }
  }
}

// ---------------------------------------------------------------------------
// Attention, double softmax, candidate-index form, 2 query-tiles per wave.
// SCAN: each staged key-tile read (2 ds_read_b128) feeds 4 MFMAs (2 q-tiles).
//   Running per-query max, quad-shared once per 64-key chunk (staleness only
//   ADDS pushes; window 12 >> needed 8). Push key indices into per-query
//   ring lists (cap 16, &-mask).
// FINISH (per q-tile, barrier-free): exact fp32 VALU dot for the ~1-2 listed
//   keys per query, exact max, l1 = sum exp (shift-invariant, candidate tail
//   < 1e-3 rel), t-1 = exp(p/l1)-1, V-row gather, add Vtot.
// ---------------------------------------------------------------------------
__global__ __launch_bounds__(256, 2)
void attn_kernel(const bf16* __restrict__ Qh, const bf16* __restrict__ Ql,
                 const bf16* __restrict__ Kh, const bf16* __restrict__ Kl,
                 const bf16* __restrict__ Vrm, const float* __restrict__ Vs,
                 bf16* __restrict__ O) {
  __shared__ __align__(16) bf16 SK[2][64][64];        // 16KB Kh stage
  __shared__ float sS[4][32][LCAP];                    // exact-s scratch
  __shared__ unsigned short sI[4][32][LCAP];           // candidate key idx
  __shared__ int pcnt[4][32];

  const int tid  = threadIdx.x;
  const int lane = tid & 63, wave = tid >> 6;
  const int c = lane & 15, quad = lane >> 4;
  const int bh = blockIdx.x;
  const int q0 = blockIdx.y * 128 + wave * 32;        // wave owns 32 queries
  const size_t hoff = (size_t)bh * SEQ * HD;
  const bf16* qh_p = Qh + hoff;
  const bf16* ql_p = Ql + hoff;
  const bf16* kh_p = Kh + hoff;
  const bf16* kl_p = Kl + hoff;
  const bf16* v_p  = Vrm + hoff;
  const f32x4 zero = {0.f, 0.f, 0.f, 0.f};

  const int sr   = tid >> 3;                          // 0..31 staging row
  const int scol = (tid & 7) * 8;
  const int sphy = ((tid & 7) ^ (sr & 7)) * 8;
  const int pc0  = ((0 + quad) ^ (c & 7)) * 8;
  const int pc1  = ((4 + quad) ^ (c & 7)) * 8;

  bf16x8 qfA[2], qlfA[2], qfB[2], qlfB[2];
#pragma unroll
  for (int t = 0; t < 2; ++t) {
    size_t offA = (size_t)(q0 + c) * HD + t * 32 + quad * 8;
    size_t offB = (size_t)(q0 + 16 + c) * HD + t * 32 + quad * 8;
    qfA[t]  = *(const bf16x8*)&qh_p[offA];
    qlfA[t] = *(const bf16x8*)&ql_p[offA];
    qfB[t]  = *(const bf16x8*)&qh_p[offB];
    qlfB[t] = *(const bf16x8*)&ql_p[offB];
  }
  if (lane < 32) pcnt[wave][lane] = 0;   // same-wave use only

  // ================= SCAN: dense hi-only, index collection =================
  bf16x8 pA = *(const bf16x8*)&kh_p[(size_t)(sr     ) * HD + scol];
  bf16x8 pB = *(const bf16x8*)&kh_p[(size_t)(sr + 32) * HD + scol];
  *(bf16x8*)&SK[0][sr     ][sphy] = pA;
  *(bf16x8*)&SK[0][sr + 32][sphy] = pB;
  __syncthreads();

  float mrA = NEG_SEED, mrB = NEG_SEED;
  int buf = 0;
  for (int cs = 0; cs < 32; ++cs) {
    if (cs < 31) {
      const size_t k0 = (size_t)(cs + 1) * 64;
      pA = *(const bf16x8*)&kh_p[(k0 + sr     ) * HD + scol];
      pB = *(const bf16x8*)&kh_p[(k0 + sr + 32) * HD + scol];
    }
#pragma unroll
    for (int t = 0; t < 4; ++t) {
      const int g = cs * 4 + t;
      bf16x8 kh0 = *(bf16x8*)&SK[buf][t * 16 + c][pc0];
      bf16x8 kh1 = *(bf16x8*)&SK[buf][t * 16 + c][pc1];
      f32x4 sA = MFMA(kh0, qfA[0], zero);
      sA = MFMA(kh1, qfA[1], sA);
      f32x4 sB = MFMA(kh0, qfB[0], zero);
      sB = MFMA(kh1, qfB[1], sB);
      const float tmA = fmaxf(fmaxf(sA[0], sA[1]), fmaxf(sA[2], sA[3]));
      const float tmB = fmaxf(fmaxf(sB[0], sB[1]), fmaxf(sB[2], sB[3]));
      mrA = fmaxf(mrA, tmA);
      mrB = fmaxf(mrB, tmB);
      if (tmA > mrA - 12.f) {
#pragma unroll
        for (int r = 0; r < 4; ++r)
          if (sA[r] > mrA - 12.f) {
            const int slot = atomicAdd(&pcnt[wave][c], 1) & (LCAP - 1);
            sI[wave][c][slot] = (unsigned short)(g * 16 + quad * 4 + r);
          }
      }
      if (tmB > mrB - 12.f) {
#pragma unroll
        for (int r = 0; r < 4; ++r)
          if (sB[r] > mrB - 12.f) {
            const int slot = atomicAdd(&pcnt[wave][16 + c], 1) & (LCAP - 1);
            sI[wave][16 + c][slot] = (unsigned short)(g * 16 + quad * 4 + r);
          }
      }
    }
    // quad-share running maxes once per chunk (staleness only adds pushes)
    mrA = fmaxf(mrA, __shfl_xor(mrA, 16, 64));
    mrA = fmaxf(mrA, __shfl_xor(mrA, 32, 64));
    mrB = fmaxf(mrB, __shfl_xor(mrB, 16, 64));
    mrB = fmaxf(mrB, __shfl_xor(mrB, 32, 64));
    if (cs < 31) {
      const int nb = buf ^ 1;
      *(bf16x8*)&SK[nb][sr     ][sphy] = pA;
      *(bf16x8*)&SK[nb][sr + 32][sphy] = pB;
      __syncthreads();
      buf = nb;
    }
  }

  // ================= FINISH: exact, per-quad, barrier-free =================
  const int b = bh >> 3, h = bh & 7;
  const float* vsp = Vs + bh * HD;

#define FINISH_Q(LQ, QF, QLF, QROW) do {                                      \
    float qv[16];                                                             \
    _Pragma("unroll")                                                         \
    for (int j = 0; j < 8; ++j) {                                             \
      qv[j]     = (float)QF[0][j] + (float)QLF[0][j];                         \
      qv[8 + j] = (float)QF[1][j] + (float)QLF[1][j];                         \
    }                                                                         \
    const int n = min(pcnt[wave][LQ], LCAP);                                  \
    float mqC = NEG_SEED;                                                     \
    for (int j = 0; j < n; ++j) {                                             \
      const int idx = sI[wave][LQ][j];                                        \
      const size_t kr = (size_t)idx * HD + quad * 8;                          \
      bf16x8 kh0 = *(const bf16x8*)&kh_p[kr];                                 \
      bf16x8 kh1 = *(const bf16x8*)&kh_p[kr + 32];                            \
      bf16x8 kl0 = *(const bf16x8*)&kl_p[kr];                                 \
      bf16x8 kl1 = *(const bf16x8*)&kl_p[kr + 32];                            \
      float s = 0.f;                                                          \
      _Pragma("unroll")                                                       \
      for (int jj = 0; jj < 8; ++jj) {                                        \
        s = fmaf(qv[jj],     (float)kh0[jj] + (float)kl0[jj], s);             \
        s = fmaf(qv[8 + jj], (float)kh1[jj] + (float)kl1[jj], s);             \
      }                                                                       \
      s += __shfl_xor(s, 16, 64);                                             \
      s += __shfl_xor(s, 32, 64);                                             \
      if (quad == 0) sS[wave][LQ][j] = s;                                     \
      mqC = fmaxf(mqC, s);                                                    \
    }                                                                         \
    float l1 = 0.f;                                                           \
    for (int j = 0; j < n; ++j) l1 += __expf(sS[wave][LQ][j] - mqC);          \
    const float inv1 = 1.f / l1;                                              \
    float oc[16];                                                             \
    _Pragma("unroll")                                                         \
    for (int i = 0; i < 16; ++i) oc[i] = 0.f;                                 \
    float l2 = 0.f;                                                           \
    for (int j = 0; j < n; ++j) {                                             \
      const float a1 = __expf(sS[wave][LQ][j] - mqC) * inv1;                  \
      const float t1 = __expf(a1) - 1.0f;                                     \
      l2 += t1;                                                               \
      const int idx = sI[wave][LQ][j];                                        \
      bf16x8 v0 = *(const bf16x8*)&v_p[(size_t)idx * HD + quad * 8];          \
      bf16x8 v1 = *(const bf16x8*)&v_p[(size_t)idx * HD + 32 + quad * 8];     \
      _Pragma("unroll")                                                       \
      for (int jj = 0; jj < 8; ++jj) {                                        \
        oc[jj]     += t1 * (float)v0[jj];                                     \
        oc[8 + jj] += t1 * (float)v1[jj];                                     \
      }                                                                       \
    }                                                                         \
    const float rcp = 1.f / (2048.f + l2);                                    \
    bf16* orow = &O[((size_t)b * SEQ + (QROW)) * EMB + h * HD];               \
    bf16x8 o0, o1;                                                            \
    _Pragma("unroll")                                                         \
    for (int jj = 0; jj < 8; ++jj) {                                          \
      o0[jj] = (bf16)((oc[jj]     + vsp[quad * 8 + jj])      * rcp);          \
      o1[jj] = (bf16)((oc[8 + jj] + vsp[32 + quad * 8 + jj]) * rcp);          \
    }                                                                         \
    *(bf16x8*)&orow[quad * 8]      = o0;                                      \
    *(bf16x8*)&orow[32 + quad * 8] = o1;                                      \
  } while (0)

  FINISH_Q(c,      qfA, qlfA, q0 + c);
  FINISH_Q(16 + c, qfB, qlfB, q0 + 16 + c);
#undef FINISH_Q
}

// ---------------------------------------------------------------------------
extern "C" void kernel_launch(void* const* d_in, const int* in_sizes, int n_in,
                              void* d_out, int out_size, void* d_ws, size_t ws_size,
                              hipStream_t stream) {
  const float* x    = (const float*)d_in[0];
  const float* Wqkv = (const float*)d_in[1];
  const float* bqkv = (const float*)d_in[2];
  const float* Wout = (const float*)d_in[3];
  const float* bout = (const float*)d_in[4];
  float* out = (float*)d_out;

  char* ws = (char*)d_ws;
  const size_t SZ = (size_t)32 * SEQ * HD * 2;  // 8 MiB per array
  bf16* Qh  = (bf16*)(ws + 0 * SZ);
  bf16* Ql  = (bf16*)(ws + 1 * SZ);
  bf16* Kh  = (bf16*)(ws + 2 * SZ);
  bf16* Kl  = (bf16*)(ws + 3 * SZ);
  bf16* Vrm = (bf16*)(ws + 4 * SZ);
  bf16* XhO = (bf16*)(ws + 5 * SZ);  // Xh during proj; overwritten by O in attn
  bf16* Xl  = (bf16*)(ws + 6 * SZ);
  bf16* Wqh = (bf16*)(ws + 7 * SZ);
  bf16* Wql = (bf16*)(ws + 7 * SZ + 0x180000);
  bf16* Wo  = (bf16*)(ws + 7 * SZ + 0x300000);
  float* Vs = (float*)(ws + 7 * SZ + 0x380000);  // 32x64 f32 Vtot (atomics)

  convert_kernel<<<dim3(2048), 256, 0, stream>>>(x, Wqkv, Wout, XhO, Xl, Wqh, Wql, Wo, Vs);
  gemm_qkv<<<dim3(1536), 256, 0, stream>>>(XhO, Xl, Wqh, Wql, bqkv, Qh, Ql, Kh, Kl, Vrm, Vs);
  attn_kernel<<<dim3(32, 16), 256, 0, stream>>>(Qh, Ql, Kh, Kl, Vrm, Vs, XhO);
  gemm_out<<<dim3(128, 8), 256, 0, stream>>>(XhO, Wo, bout, out);
}